// Round 6
// baseline (128.538 us; speedup 1.0000x reference)
//
#include <hip/hip_runtime.h>
#include <hip/hip_bf16.h>

// Problem constants
#define BB 2
#define SS 2048
#define DD 1024
#define HH 16
#define DKK 64

typedef __attribute__((ext_vector_type(4))) float  f32x4;
typedef __attribute__((ext_vector_type(8))) short  s16x8;
typedef __attribute__((ext_vector_type(4))) short  s16x4;
typedef __attribute__((ext_vector_type(4))) float  fvec4;

__device__ __forceinline__ short f2bs(float f) {
    union { __hip_bfloat16 b; short s; } u;
    u.b = __float2bfloat16(f);
    return u.s;
}

__device__ __forceinline__ void gload_lds16(const short* g, short* l) {
    __builtin_amdgcn_global_load_lds((const __attribute__((address_space(1))) void*)g,
                                     (__attribute__((address_space(3))) void*)l, 16, 0, 0);
}

// ---------------------------------------------------------------------------
// fp32 -> bf16 convert, 7 tensors in one launch (blockIdx.y selects tensor)
// ---------------------------------------------------------------------------
__global__ __launch_bounds__(256) void cvt_all(
    const float* __restrict__ q,  const float* __restrict__ k,  const float* __restrict__ v,
    const float* __restrict__ wq, const float* __restrict__ wk, const float* __restrict__ wv,
    const float* __restrict__ wo,
    short* __restrict__ qo,  short* __restrict__ ko,  short* __restrict__ vo,
    short* __restrict__ wqo, short* __restrict__ wko, short* __restrict__ wvo,
    short* __restrict__ woo)
{
    const float* src; short* dst; int n;
    switch (blockIdx.y) {
        case 0: src = q;  dst = qo;  n = BB * SS * DD; break;
        case 1: src = k;  dst = ko;  n = BB * SS * DD; break;
        case 2: src = v;  dst = vo;  n = BB * SS * DD; break;
        case 3: src = wq; dst = wqo; n = DD * DD; break;
        case 4: src = wk; dst = wko; n = DD * DD; break;
        case 5: src = wv; dst = wvo; n = DD * DD; break;
        default: src = wo; dst = woo; n = DD * DD; break;
    }
    int i = (blockIdx.x * 256 + threadIdx.x) * 8;
    const int stride = gridDim.x * 256 * 8;
    for (; i < n; i += stride) {
        fvec4 a = *(const fvec4*)&src[i];
        fvec4 b = *(const fvec4*)&src[i + 4];
        s16x8 o;
        o[0] = f2bs(a[0]); o[1] = f2bs(a[1]); o[2] = f2bs(a[2]); o[3] = f2bs(a[3]);
        o[4] = f2bs(b[0]); o[5] = f2bs(b[1]); o[6] = f2bs(b[2]); o[7] = f2bs(b[3]);
        *(s16x8*)&dst[i] = o;
    }
}

// ---------------------------------------------------------------------------
// GEMM v2 (NT), bf16: C[M,N] = (A[M,K(sel)] * Bw[N,K]^T + bias) * oscale
// 128x128 tile, BK=64 (half the barriers of BK=32), 4 waves each 64x64.
// T2 both-sides swizzle (rule #21): global_load_lds with LINEAR LDS dest +
// source chunk XOR (chunk ^= row&7); ds_read applies the same XOR ->
// fragment reads spread over all 8 bank-quads (2-way, free) instead of the
// 8/16-way conflict of a linear row-major tile.
// 1D grid, XCD-aware decode: each output panel's 8 x-blocks land on ONE XCD
// (round-robin dispatch assumption; wrong mapping only costs locality).
// z (= panel / NY) selects tensor triple {A,B,bias,O,oscale,koff} -> used
// for fused QKV (z=tensor) and split-K O-proj (z=K-half, bias=null).
// ---------------------------------------------------------------------------
template<bool OUTF32>
__global__ __launch_bounds__(256) void gemm_nt_v2(
    const short* __restrict__ A0, const short* __restrict__ A1, const short* __restrict__ A2,
    const short* __restrict__ B0, const short* __restrict__ B1, const short* __restrict__ B2,
    const float* __restrict__ c0, const float* __restrict__ c1, const float* __restrict__ c2,
    void* __restrict__ O0, void* __restrict__ O1, void* __restrict__ O2,
    float os0, float os1, float os2,
    int ko0, int ko1, int ko2,
    int ppx, int NY, int KL, int N, int K)
{
    // XCD-aware decode (NX = 8 fixed: N=1024, BN=128)
    const int d   = blockIdx.x;
    const int xcd = d & 7;
    const int s   = d >> 3;
    const int x   = s & 7;
    const int pl  = s >> 3;              // 0..ppx-1
    const int panel = xcd * ppx + pl;    // 0..NY*NZ-1
    const int y   = panel % NY;
    const int z   = panel / NY;

    const short* A    = z == 0 ? A0 : (z == 1 ? A1 : A2);
    const short* Bw   = z == 0 ? B0 : (z == 1 ? B1 : B2);
    const float* bias = z == 0 ? c0 : (z == 1 ? c1 : c2);
    void* Cp          = z == 0 ? O0 : (z == 1 ? O1 : O2);
    const float oscale = z == 0 ? os0 : (z == 1 ? os1 : os2);
    const int koff     = z == 0 ? ko0 : (z == 1 ? ko1 : ko2);

    __shared__ short As[128][64];
    __shared__ short Bs[128][64];

    const int tid  = threadIdx.x;
    const int lane = tid & 63;
    const int wid  = tid >> 6;
    const int r16  = lane & 15;
    const int g    = lane >> 4;
    const int m0   = y * 128;
    const int n0   = x * 128;
    const int wr   = (wid >> 1) * 64;
    const int wc   = (wid & 1) * 64;
    const int srow8 = lane >> 3;         // 0..7 (row within 8-row stage group)
    const int c8    = lane & 7;          // chunk 0..7

    f32x4 acc[4][4];
#pragma unroll
    for (int mi = 0; mi < 4; ++mi)
#pragma unroll
        for (int ni = 0; ni < 4; ++ni) acc[mi][ni] = (f32x4){0.f, 0.f, 0.f, 0.f};

    const int csrc = (c8 ^ srow8) * 8;   // source-swizzled chunk (row&7 == srow8)
    const int nk = KL >> 6;
#pragma unroll 1
    for (int kt = 0; kt < nk; ++kt) {
        const int k0 = koff + kt * 64;
        if (kt) __syncthreads();
        // --- stage A and B 128x64 tiles, source-swizzled, linear LDS dest ---
#pragma unroll
        for (int q = 0; q < 4; ++q) {
            const int r = wid * 32 + q * 8 + srow8;
            gload_lds16(&A[(size_t)(m0 + r) * K + k0 + csrc], &As[wid * 32 + q * 8][0]);
        }
#pragma unroll
        for (int q = 0; q < 4; ++q) {
            const int r = wid * 32 + q * 8 + srow8;
            gload_lds16(&Bw[(size_t)(n0 + r) * K + k0 + csrc], &Bs[wid * 32 + q * 8][0]);
        }
        __syncthreads();   // drains vmcnt (compiler emits full waitcnt before barrier)

#pragma unroll
        for (int kk = 0; kk < 2; ++kk) {
            s16x8 af[4], bf[4];
#pragma unroll
            for (int mi = 0; mi < 4; ++mi) {
                const int row = wr + mi * 16 + r16;
                af[mi] = *(const s16x8*)&As[row][((kk * 4 + g) ^ (row & 7)) * 8];
            }
#pragma unroll
            for (int ni = 0; ni < 4; ++ni) {
                const int row = wc + ni * 16 + r16;
                bf[ni] = *(const s16x8*)&Bs[row][((kk * 4 + g) ^ (row & 7)) * 8];
            }
#pragma unroll
            for (int mi = 0; mi < 4; ++mi)
#pragma unroll
                for (int ni = 0; ni < 4; ++ni)
                    acc[mi][ni] = __builtin_amdgcn_mfma_f32_16x16x32_bf16(
                        af[mi], bf[ni], acc[mi][ni], 0, 0, 0);
        }
    }

    // epilogue: (acc + bias) * oscale; C/D: col = l&15, row = (l>>4)*4 + r
#pragma unroll
    for (int ni = 0; ni < 4; ++ni) {
        const int col = n0 + wc + ni * 16 + r16;
        const float bv = bias ? bias[col] : 0.f;
#pragma unroll
        for (int mi = 0; mi < 4; ++mi) {
#pragma unroll
            for (int r = 0; r < 4; ++r) {
                const int row = m0 + wr + mi * 16 + g * 4 + r;
                const float vv = (acc[mi][ni][r] + bv) * oscale;
                if constexpr (OUTF32)
                    ((float*)Cp)[(size_t)row * N + col] = vv;
                else
                    ((short*)Cp)[(size_t)row * N + col] = f2bs(vv);
            }
        }
    }
}

// ---------------------------------------------------------------------------
// Split-K combine for O-projection: out = P0 + P1 + bias
// ---------------------------------------------------------------------------
__global__ __launch_bounds__(256) void combine_o(
    const float* __restrict__ P0, const float* __restrict__ P1,
    const float* __restrict__ bo, float* __restrict__ out)
{
    const int n = BB * SS * DD;
    int i = (blockIdx.x * 256 + threadIdx.x) * 8;
    const int stride = gridDim.x * 256 * 8;
    for (; i < n; i += stride) {
        fvec4 a0 = *(const fvec4*)&P0[i];
        fvec4 a1 = *(const fvec4*)&P0[i + 4];
        fvec4 b0 = *(const fvec4*)&P1[i];
        fvec4 b1 = *(const fvec4*)&P1[i + 4];
        fvec4 c0 = *(const fvec4*)&bo[i & (DD - 1)];
        fvec4 c1 = *(const fvec4*)&bo[(i + 4) & (DD - 1)];
        fvec4 o0 = a0 + b0 + c0;
        fvec4 o1 = a1 + b1 + c1;
        *(fvec4*)&out[i] = o0;
        *(fvec4*)&out[i + 4] = o1;
    }
}

// ---------------------------------------------------------------------------
// Per-head V transpose: vp (head-major [bh][s][dk]) -> vT ([bh][dk][s])
// ---------------------------------------------------------------------------
__global__ __launch_bounds__(256) void mha_transpose_v(
    const short* __restrict__ vp, short* __restrict__ vT)
{
    const int st = blockIdx.x;
    const int bh = blockIdx.y;
    const short* src = vp + (size_t)bh * SS * DKK;
    short*       dst = vT + (size_t)bh * SS * DKK;
    const int tid = threadIdx.x;
#pragma unroll
    for (int i = 0; i < 2; ++i) {
        const int c  = tid + i * 256;   // 0..511
        const int dk = c >> 3;          // 0..63
        const int sc = c & 7;           // 0..7
        const int s0 = st * 64 + sc * 8;
        s16x8 v;
#pragma unroll
        for (int j = 0; j < 8; ++j) v[j] = src[(size_t)(s0 + j) * DKK + dk];
        *(s16x8*)&dst[(size_t)dk * SS + s0] = v;
    }
}

// ---------------------------------------------------------------------------
// Flash attention (causal), buggy-reshape head layout -- LDS-SHARED K/V.
// (unchanged from round 5: 512 blocks, K/V staged once per block per k-tile
// via source-swizzled global_load_lds; head pinned to XCD via bh%8.)
// ---------------------------------------------------------------------------
__global__ __launch_bounds__(256, 2) void mha_attn(
    const short* __restrict__ qp, const short* __restrict__ kp,
    const short* __restrict__ vT, short* __restrict__ ctx)
{
    __shared__ short Ks[64][64];     // [key][dk]   (chunk-swizzled)
    __shared__ short Vs[64][64];     // [dv][key]   (chunk-swizzled)
    __shared__ short P[4][16][72];   // per-wave P, padded rows

    const int tid  = threadIdx.x;
    const int wid  = tid >> 6;
    const int lane = tid & 63;
    const int r16  = lane & 15;
    const int g    = lane >> 4;

    const int bh  = blockIdx.x;   // 0..31 -> XCD = bh%8 (head pinned to XCD)
    const int bxp = blockIdx.y;   // 0..15
    const int b   = bh >> 4;
    const int h   = bh & 15;

    const short* Qh = qp + (size_t)bh * SS * DKK;
    const short* Kh = kp + (size_t)bh * SS * DKK;
    const short* Vh = vT + (size_t)bh * SS * DKK;   // [DK][S]

    // staging coords (per lane, fixed): 8 rows x 8 chunks per instr
    const int srow = lane >> 3;          // 0..7
    const int r0   = wid * 16;           // wave's 16-row stripe

#pragma unroll 1
    for (int t = 0; t < 2; ++t) {
        const int grp = t ? (31 - bxp) : bxp;     // 64-row q-group index
        const int qr0 = grp * 64 + wid * 16;
        const int nkt = grp + 1;

        const s16x8 qf0 = *(const s16x8*)&Qh[(size_t)(qr0 + r16) * DKK + g * 8];
        const s16x8 qf1 = *(const s16x8*)&Qh[(size_t)(qr0 + r16) * DKK + 32 + g * 8];

        f32x4 po[4];
#pragma unroll
        for (int i = 0; i < 4; ++i) po[i] = (f32x4){0.f, 0.f, 0.f, 0.f};
        float l_[4] = {0.f, 0.f, 0.f, 0.f};

#pragma unroll 1
        for (int j = 0; j < nkt; ++j) {
            const int k0 = j * 64;
            __syncthreads();   // protect Ks/Vs (and P across groups)
            // ---- stage K and Vt tiles (16KB), source-swizzled ----
            {
                const int rowA = r0 + srow;
                const int rowB = rowA + 8;
                const int cA = (((lane & 7) ^ (rowA & 7)) & 7) * 8;
                const int cB = (((lane & 7) ^ (rowB & 7)) & 7) * 8;
                gload_lds16(&Kh[(size_t)(k0 + rowA) * DKK + cA], &Ks[r0][0]);
                gload_lds16(&Kh[(size_t)(k0 + rowB) * DKK + cB], &Ks[r0 + 8][0]);
                gload_lds16(&Vh[(size_t)rowA * SS + k0 + cA], &Vs[r0][0]);
                gload_lds16(&Vh[(size_t)rowB * SS + k0 + cB], &Vs[r0 + 8][0]);
            }
            __syncthreads();   // drain vmcnt: tiles ready

            // ---- QK^T from LDS (swizzled reads) ----
            f32x4 sc[4];
            __builtin_amdgcn_s_setprio(1);
#pragma unroll
            for (int cg = 0; cg < 4; ++cg) {
                const int R  = cg * 16 + r16;
                const int sw = R & 7;
                const s16x8 kf0 = *(const s16x8*)&Ks[R][((g ^ sw) & 7) * 8];
                const s16x8 kf1 = *(const s16x8*)&Ks[R][(((4 + g) ^ sw) & 7) * 8];
                f32x4 tt = (f32x4){0.f, 0.f, 0.f, 0.f};
                tt = __builtin_amdgcn_mfma_f32_16x16x32_bf16(qf0, kf0, tt, 0, 0, 0);
                tt = __builtin_amdgcn_mfma_f32_16x16x32_bf16(qf1, kf1, tt, 0, 0, 0);
                sc[cg] = tt;
            }
            __builtin_amdgcn_s_setprio(0);

            // ---- causal mask (diag tile = last tile of the group) ----
            if (j == nkt - 1) {
#pragma unroll
                for (int cg = 0; cg < 4; ++cg)
#pragma unroll
                    for (int r = 0; r < 4; ++r)
                        if (k0 + cg * 16 + r16 > qr0 + g * 4 + r) sc[cg][r] = -1e9f;
            }
            // ---- softmax-lite: exp + per-lane partial sums + P write ----
#pragma unroll
            for (int cg = 0; cg < 4; ++cg)
#pragma unroll
                for (int r = 0; r < 4; ++r) {
                    const float p = __expf(sc[cg][r]);
                    l_[r] += p;
                    P[wid][g * 4 + r][cg * 16 + r16] = f2bs(p);
                }
            // same-wave write->read: compiler inserts lgkmcnt wait
            const s16x8 pf0 = *(const s16x8*)&P[wid][r16][g * 8];
            const s16x8 pf1 = *(const s16x8*)&P[wid][r16][32 + g * 8];

            // ---- PV from LDS Vt (swizzled reads) ----
            __builtin_amdgcn_s_setprio(1);
#pragma unroll
            for (int dg = 0; dg < 4; ++dg) {
                const int Rv = dg * 16 + r16;
                const int sw = Rv & 7;
                const s16x8 vf0 = *(const s16x8*)&Vs[Rv][((g ^ sw) & 7) * 8];
                const s16x8 vf1 = *(const s16x8*)&Vs[Rv][(((4 + g) ^ sw) & 7) * 8];
                po[dg] = __builtin_amdgcn_mfma_f32_16x16x32_bf16(pf0, vf0, po[dg], 0, 0, 0);
                po[dg] = __builtin_amdgcn_mfma_f32_16x16x32_bf16(pf1, vf1, po[dg], 0, 0, 0);
            }
            __builtin_amdgcn_s_setprio(0);
        }

        // ---- epilogue: reduce row sums across 16 lanes, normalize, store ----
#pragma unroll
        for (int r = 0; r < 4; ++r) {
#pragma unroll
            for (int off = 1; off < 16; off <<= 1)
                l_[r] += __shfl_xor(l_[r], off);
        }
#pragma unroll
        for (int dg = 0; dg < 4; ++dg)
#pragma unroll
            for (int r = 0; r < 4; ++r) {
                const int srw = qr0 + g * 4 + r;
                const float v = po[dg][r] * __builtin_amdgcn_rcpf(l_[r]);
                ctx[((size_t)(b * SS + srw)) * DD + h * 64 + dg * 16 + r16] = f2bs(v);
            }
    }
}

// ---------------------------------------------------------------------------
extern "C" void kernel_launch(void* const* d_in, const int* in_sizes, int n_in,
                              void* d_out, int out_size, void* d_ws, size_t ws_size,
                              hipStream_t stream) {
    const float* query = (const float*)d_in[0];
    const float* key   = (const float*)d_in[1];
    const float* value = (const float*)d_in[2];
    // d_in[3] = mask (causal tril) -- implemented analytically
    const float* Wq = (const float*)d_in[4];
    const float* bq = (const float*)d_in[5];
    const float* Wk = (const float*)d_in[6];
    const float* bk = (const float*)d_in[7];
    const float* Wv = (const float*)d_in[8];
    const float* bv = (const float*)d_in[9];
    const float* Wo = (const float*)d_in[10];
    const float* bo = (const float*)d_in[11];
    float* out = (float*)d_out;

    const size_t elems = (size_t)BB * SS * DD;   // 4M
    const size_t wel   = (size_t)DD * DD;        // 1M
    short* qx  = (short*)d_ws;        // bf16 inputs
    short* kx  = qx + elems;
    short* vx  = kx + elems;
    short* wqx = vx + elems;          // bf16 weights
    short* wkx = wqx + wel;
    short* wvx = wkx + wel;
    short* wox = wvx + wel;
    short* qp  = wox + wel;           // projections
    short* kp  = qp + elems;
    short* vp  = kp + elems;
    // aliases (lifetime-disjoint):
    short* vT  = qx;                  // qx dead after QKV GEMM
    short* ctx = vx;                  // vx dead after QKV GEMM
    float* P0  = (float*)qx;          // spans qx+kx (16MB), dead after attn
    float* P1  = (float*)qp;          // spans qp+kp (16MB), dead after attn

    const int M = BB * SS;   // 4096

    // 1) convert everything to bf16
    cvt_all<<<dim3(1024, 7), 256, 0, stream>>>(query, key, value, Wq, Wk, Wv, Wo,
                                               qx, kx, vx, wqx, wkx, wvx, wox);
    // 2) fused Q/K/V projections (768 blocks, XCD-panel decode, BK=64,
    //    swizzled LDS); 1/sqrt(DK) folded into Q
    gemm_nt_v2<false><<<dim3(768), 256, 0, stream>>>(
        qx, kx, vx, wqx, wkx, wvx, bq, bk, bv, qp, kp, vp,
        0.125f, 1.0f, 1.0f, 0, 0, 0, /*ppx=*/12, /*NY=*/32, /*KL=*/1024, DD, DD);
    // 3) V transpose per head (vT = qx region; qx input dead after step 2)
    mha_transpose_v<<<dim3(SS / 64, BB * HH), 256, 0, stream>>>(vp, vT);
    // 4) attention -> ctx (= vx region)
    mha_attn<<<dim3(BB * HH, 16), 256, 0, stream>>>(qp, kp, vT, ctx);
    // 5) output projection, split-K=2 (512 blocks = 2/CU), fp32 partials
    gemm_nt_v2<true><<<dim3(512), 256, 0, stream>>>(
        ctx, ctx, ctx, wox, wox, wox, nullptr, nullptr, nullptr,
        (void*)P0, (void*)P1, (void*)P1,
        1.0f, 1.0f, 1.0f, /*ko=*/0, 512, 512, /*ppx=*/8, /*NY=*/32, /*KL=*/512, DD, DD);
    // 6) combine partials + bias -> out
    combine_o<<<dim3(2048), 256, 0, stream>>>(P0, P1, bo, out);
}

// Round 8
// 121.200 us; speedup vs baseline: 1.0605x; 1.0605x over previous
//
#include <hip/hip_runtime.h>
#include <hip/hip_bf16.h>

// Problem constants
#define BB 2
#define SS 2048
#define DD 1024
#define HH 16
#define DKK 64

typedef __attribute__((ext_vector_type(4))) float  f32x4;
typedef __attribute__((ext_vector_type(8))) short  s16x8;
typedef __attribute__((ext_vector_type(4))) short  s16x4;
typedef __attribute__((ext_vector_type(4))) float  fvec4;

__device__ __forceinline__ short f2bs(float f) {
    union { __hip_bfloat16 b; short s; } u;
    u.b = __float2bfloat16(f);
    return u.s;
}

__device__ __forceinline__ void gload_lds16(const short* g, short* l) {
    __builtin_amdgcn_global_load_lds((const __attribute__((address_space(1))) void*)g,
                                     (__attribute__((address_space(3))) void*)l, 16, 0, 0);
}

// ---------------------------------------------------------------------------
// fp32 -> bf16 convert, 7 tensors in one launch (blockIdx.y selects tensor)
// ---------------------------------------------------------------------------
__global__ __launch_bounds__(256) void cvt_all(
    const float* __restrict__ q,  const float* __restrict__ k,  const float* __restrict__ v,
    const float* __restrict__ wq, const float* __restrict__ wk, const float* __restrict__ wv,
    const float* __restrict__ wo,
    short* __restrict__ qo,  short* __restrict__ ko,  short* __restrict__ vo,
    short* __restrict__ wqo, short* __restrict__ wko, short* __restrict__ wvo,
    short* __restrict__ woo)
{
    const float* src; short* dst; int n;
    switch (blockIdx.y) {
        case 0: src = q;  dst = qo;  n = BB * SS * DD; break;
        case 1: src = k;  dst = ko;  n = BB * SS * DD; break;
        case 2: src = v;  dst = vo;  n = BB * SS * DD; break;
        case 3: src = wq; dst = wqo; n = DD * DD; break;
        case 4: src = wk; dst = wko; n = DD * DD; break;
        case 5: src = wv; dst = wvo; n = DD * DD; break;
        default: src = wo; dst = woo; n = DD * DD; break;
    }
    int i = (blockIdx.x * 256 + threadIdx.x) * 8;
    const int stride = gridDim.x * 256 * 8;
    for (; i < n; i += stride) {
        fvec4 a = *(const fvec4*)&src[i];
        fvec4 b = *(const fvec4*)&src[i + 4];
        s16x8 o;
        o[0] = f2bs(a[0]); o[1] = f2bs(a[1]); o[2] = f2bs(a[2]); o[3] = f2bs(a[3]);
        o[4] = f2bs(b[0]); o[5] = f2bs(b[1]); o[6] = f2bs(b[2]); o[7] = f2bs(b[3]);
        *(s16x8*)&dst[i] = o;
    }
}

// ---------------------------------------------------------------------------
// GEMM v2 (NT), bf16: C[M,N] = (A[M,K] * Bw[N,K]^T + bias) * oscale
// 128xBN tile, BK=64, 4 waves. T2 both-sides swizzle (source-chunk XOR +
// same XOR on ds_read; linear LDS dest for global_load_lds).
// 1D grid, XCD-aware decode. z = panel/NY selects tensor triple.
// BN=128 (NXSH=3): QKV fused, wave 64x64 (4x4).
// BN=64  (NXSH=4): O-proj direct, wave 64x32 (4x2), 512 blocks.
// FIX r7->r8: B-stage row base is wid*(BN/4) (r7's wid*(BN/8) overlapped
// waves and left rows unstaged -> garbage LDS -> NaN).
// ---------------------------------------------------------------------------
template<int BN, int NXSH, bool OUTF32>
__global__ __launch_bounds__(256) void gemm_nt_v2(
    const short* __restrict__ A0, const short* __restrict__ A1, const short* __restrict__ A2,
    const short* __restrict__ B0, const short* __restrict__ B1, const short* __restrict__ B2,
    const float* __restrict__ c0, const float* __restrict__ c1, const float* __restrict__ c2,
    void* __restrict__ O0, void* __restrict__ O1, void* __restrict__ O2,
    float os0, float os1, float os2,
    int ppx, int NY, int KL, int N, int K)
{
    const int d   = blockIdx.x;
    const int xcd = d & 7;
    const int s   = d >> 3;
    const int x   = s & ((1 << NXSH) - 1);
    const int pl  = s >> NXSH;
    const int panel = xcd * ppx + pl;
    const int y   = panel % NY;
    const int z   = panel / NY;

    const short* A    = z == 0 ? A0 : (z == 1 ? A1 : A2);
    const short* Bw   = z == 0 ? B0 : (z == 1 ? B1 : B2);
    const float* bias = z == 0 ? c0 : (z == 1 ? c1 : c2);
    void* Cp          = z == 0 ? O0 : (z == 1 ? O1 : O2);
    const float oscale = z == 0 ? os0 : (z == 1 ? os1 : os2);

    __shared__ short As[128][64];
    __shared__ short Bs[BN][64];

    const int tid  = threadIdx.x;
    const int lane = tid & 63;
    const int wid  = tid >> 6;
    const int r16  = lane & 15;
    const int g    = lane >> 4;
    const int m0   = y * 128;
    const int n0   = x * BN;
    constexpr int MR = 4;
    constexpr int NR = BN / 32;          // 128->4, 64->2
    const int wr   = (wid >> 1) * 64;
    const int wc   = (wid & 1) * (BN / 2);
    const int srow8 = lane >> 3;         // 0..7
    const int c8    = lane & 7;          // chunk 0..7

    f32x4 acc[MR][NR];
#pragma unroll
    for (int mi = 0; mi < MR; ++mi)
#pragma unroll
        for (int ni = 0; ni < NR; ++ni) acc[mi][ni] = (f32x4){0.f, 0.f, 0.f, 0.f};

    const int csrc = (c8 ^ srow8) * 8;   // source-swizzled chunk
    const int nk = KL >> 6;
#pragma unroll 1
    for (int kt = 0; kt < nk; ++kt) {
        const int k0 = kt * 64;
        if (kt) __syncthreads();
        // --- stage A 128x64: wave covers rows [wid*32, wid*32+32) ---
#pragma unroll
        for (int q = 0; q < 4; ++q) {
            const int r = wid * 32 + q * 8 + srow8;
            gload_lds16(&A[(size_t)(m0 + r) * K + k0 + csrc], &As[wid * 32 + q * 8][0]);
        }
        // --- stage B BNx64: wave covers rows [wid*(BN/4), +BN/4) ---
#pragma unroll
        for (int q = 0; q < BN / 32; ++q) {
            const int r = wid * (BN / 4) + q * 8 + srow8;
            gload_lds16(&Bw[(size_t)(n0 + r) * K + k0 + csrc], &Bs[wid * (BN / 4) + q * 8][0]);
        }
        __syncthreads();   // drains vmcnt

#pragma unroll
        for (int kk = 0; kk < 2; ++kk) {
            s16x8 af[MR], bf[NR];
#pragma unroll
            for (int mi = 0; mi < MR; ++mi) {
                const int row = wr + mi * 16 + r16;
                af[mi] = *(const s16x8*)&As[row][((kk * 4 + g) ^ (row & 7)) * 8];
            }
#pragma unroll
            for (int ni = 0; ni < NR; ++ni) {
                const int row = wc + ni * 16 + r16;
                bf[ni] = *(const s16x8*)&Bs[row][((kk * 4 + g) ^ (row & 7)) * 8];
            }
#pragma unroll
            for (int mi = 0; mi < MR; ++mi)
#pragma unroll
                for (int ni = 0; ni < NR; ++ni)
                    acc[mi][ni] = __builtin_amdgcn_mfma_f32_16x16x32_bf16(
                        af[mi], bf[ni], acc[mi][ni], 0, 0, 0);
        }
    }

#pragma unroll
    for (int ni = 0; ni < NR; ++ni) {
        const int col = n0 + wc + ni * 16 + r16;
        const float bv = bias ? bias[col] : 0.f;
#pragma unroll
        for (int mi = 0; mi < MR; ++mi) {
#pragma unroll
            for (int r = 0; r < 4; ++r) {
                const int row = m0 + wr + mi * 16 + g * 4 + r;
                const float vv = (acc[mi][ni][r] + bv) * oscale;
                if constexpr (OUTF32)
                    ((float*)Cp)[(size_t)row * N + col] = vv;
                else
                    ((short*)Cp)[(size_t)row * N + col] = f2bs(vv);
            }
        }
    }
}

// ---------------------------------------------------------------------------
// Per-head V transpose: vp (head-major [bh][s][dk]) -> vT ([bh][dk][s])
// ---------------------------------------------------------------------------
__global__ __launch_bounds__(256) void mha_transpose_v(
    const short* __restrict__ vp, short* __restrict__ vT)
{
    const int st = blockIdx.x;
    const int bh = blockIdx.y;
    const short* src = vp + (size_t)bh * SS * DKK;
    short*       dst = vT + (size_t)bh * SS * DKK;
    const int tid = threadIdx.x;
#pragma unroll
    for (int i = 0; i < 2; ++i) {
        const int c  = tid + i * 256;   // 0..511
        const int dk = c >> 3;          // 0..63
        const int sc = c & 7;           // 0..7
        const int s0 = st * 64 + sc * 8;
        s16x8 v;
#pragma unroll
        for (int j = 0; j < 8; ++j) v[j] = src[(size_t)(s0 + j) * DKK + dk];
        *(s16x8*)&dst[(size_t)dk * SS + s0] = v;
    }
}

// ---------------------------------------------------------------------------
// Flash attention v3 (causal), buggy-reshape head layout.
// Double-buffered Ks/Vs; next tile's 4 global_load_lds issued before the
// current tile's compute; counted s_waitcnt vmcnt(4) (never 0 in main loop)
// + raw s_barrier; lgkmcnt(0)+barrier at tile end releases the buffer.
// Per-wave vmcnt is safe: each wave waits its own 4 current-tile loads, the
// barrier makes it global. Epilogue stores only inflate vmcnt (wait longer).
// Grid (bh=32, bx=16): bh%8 pins each head's K/V to one XCD L2;
// (bxp, 31-bxp) pairing -> 33 k-tiles per block, perfectly balanced.
// ---------------------------------------------------------------------------
__global__ __launch_bounds__(256, 2) void mha_attn(
    const short* __restrict__ qp, const short* __restrict__ kp,
    const short* __restrict__ vT, short* __restrict__ ctx)
{
    __shared__ short Ks[2][64][64];   // [buf][key][dk]   (chunk-swizzled)
    __shared__ short Vs[2][64][64];   // [buf][dv][key]   (chunk-swizzled)
    __shared__ short P[4][16][72];    // per-wave P, padded rows

    const int tid  = threadIdx.x;
    const int wid  = tid >> 6;
    const int lane = tid & 63;
    const int r16  = lane & 15;
    const int g    = lane >> 4;

    const int bh  = blockIdx.x;   // 0..31 -> XCD = bh%8
    const int bxp = blockIdx.y;   // 0..15
    const int b   = bh >> 4;
    const int h   = bh & 15;

    const short* Qh = qp + (size_t)bh * SS * DKK;
    const short* Kh = kp + (size_t)bh * SS * DKK;
    const short* Vh = vT + (size_t)bh * SS * DKK;   // [DK][S]

    const int srow = lane >> 3;                     // 0..7
    const int csw  = (((lane & 7) ^ srow) & 7) * 8; // source-swizzled chunk
    const int r0   = wid * 16;                      // wave's 16-row stripe

    auto STAGE = [&](int buf, int j) {
        const int k0 = j * 64;
        const int rA = r0 + srow;
        const int rB = rA + 8;
        gload_lds16(&Kh[(size_t)(k0 + rA) * DKK + csw], &Ks[buf][r0][0]);
        gload_lds16(&Kh[(size_t)(k0 + rB) * DKK + csw], &Ks[buf][r0 + 8][0]);
        gload_lds16(&Vh[(size_t)rA * SS + k0 + csw],    &Vs[buf][r0][0]);
        gload_lds16(&Vh[(size_t)rB * SS + k0 + csw],    &Vs[buf][r0 + 8][0]);
    };

#pragma unroll 1
    for (int t = 0; t < 2; ++t) {
        const int grp = t ? (31 - bxp) : bxp;     // 64-row q-group index
        const int qr0 = grp * 64 + wid * 16;
        const int nkt = grp + 1;

        const s16x8 qf0 = *(const s16x8*)&Qh[(size_t)(qr0 + r16) * DKK + g * 8];
        const s16x8 qf1 = *(const s16x8*)&Qh[(size_t)(qr0 + r16) * DKK + 32 + g * 8];

        f32x4 po[4];
#pragma unroll
        for (int i = 0; i < 4; ++i) po[i] = (f32x4){0.f, 0.f, 0.f, 0.f};
        float l_[4] = {0.f, 0.f, 0.f, 0.f};

        STAGE(0, 0);   // prologue: tile 0 into buffer 0

#pragma unroll 1
        for (int j = 0; j < nkt; ++j) {
            const int cur = j & 1;
            const int k0 = j * 64;
            // ---- issue next tile's loads, then wait only for current's ----
            if (j + 1 < nkt) {
                STAGE(cur ^ 1, j + 1);
                asm volatile("s_waitcnt vmcnt(4)" ::: "memory");
            } else {
                asm volatile("s_waitcnt vmcnt(0)" ::: "memory");
            }
            __builtin_amdgcn_s_barrier();        // all waves: buf[cur] ready
            __builtin_amdgcn_sched_barrier(0);

            // ---- QK^T from LDS (swizzled reads) ----
            f32x4 sc[4];
            __builtin_amdgcn_s_setprio(1);
#pragma unroll
            for (int cg = 0; cg < 4; ++cg) {
                const int R  = cg * 16 + r16;
                const int sw = R & 7;
                const s16x8 kf0 = *(const s16x8*)&Ks[cur][R][((g ^ sw) & 7) * 8];
                const s16x8 kf1 = *(const s16x8*)&Ks[cur][R][(((4 + g) ^ sw) & 7) * 8];
                f32x4 tt = (f32x4){0.f, 0.f, 0.f, 0.f};
                tt = __builtin_amdgcn_mfma_f32_16x16x32_bf16(qf0, kf0, tt, 0, 0, 0);
                tt = __builtin_amdgcn_mfma_f32_16x16x32_bf16(qf1, kf1, tt, 0, 0, 0);
                sc[cg] = tt;
            }
            __builtin_amdgcn_s_setprio(0);

            // ---- causal mask (diag tile = last tile of the group) ----
            if (j == nkt - 1) {
#pragma unroll
                for (int cg = 0; cg < 4; ++cg)
#pragma unroll
                    for (int r = 0; r < 4; ++r)
                        if (k0 + cg * 16 + r16 > qr0 + g * 4 + r) sc[cg][r] = -1e9f;
            }
            // ---- softmax-lite: exp + per-lane partial sums + P write ----
#pragma unroll
            for (int cg = 0; cg < 4; ++cg)
#pragma unroll
                for (int r = 0; r < 4; ++r) {
                    const float p = __expf(sc[cg][r]);
                    l_[r] += p;
                    P[wid][g * 4 + r][cg * 16 + r16] = f2bs(p);
                }
            // same-wave write->read: compiler inserts lgkmcnt wait
            const s16x8 pf0 = *(const s16x8*)&P[wid][r16][g * 8];
            const s16x8 pf1 = *(const s16x8*)&P[wid][r16][32 + g * 8];

            // ---- PV from LDS Vt (swizzled reads) ----
            __builtin_amdgcn_s_setprio(1);
#pragma unroll
            for (int dg = 0; dg < 4; ++dg) {
                const int Rv = dg * 16 + r16;
                const int sw = Rv & 7;
                const s16x8 vf0 = *(const s16x8*)&Vs[cur][Rv][((g ^ sw) & 7) * 8];
                const s16x8 vf1 = *(const s16x8*)&Vs[cur][Rv][(((4 + g) ^ sw) & 7) * 8];
                po[dg] = __builtin_amdgcn_mfma_f32_16x16x32_bf16(pf0, vf0, po[dg], 0, 0, 0);
                po[dg] = __builtin_amdgcn_mfma_f32_16x16x32_bf16(pf1, vf1, po[dg], 0, 0, 0);
            }
            __builtin_amdgcn_s_setprio(0);

            // ---- tile end: LDS reads retired, then release the buffer ----
            __builtin_amdgcn_sched_barrier(0);
            asm volatile("s_waitcnt lgkmcnt(0)" ::: "memory");
            __builtin_amdgcn_s_barrier();
        }

        // ---- epilogue: reduce row sums across 16 lanes, normalize, store ----
#pragma unroll
        for (int r = 0; r < 4; ++r) {
#pragma unroll
            for (int off = 1; off < 16; off <<= 1)
                l_[r] += __shfl_xor(l_[r], off);
        }
#pragma unroll
        for (int dg = 0; dg < 4; ++dg)
#pragma unroll
            for (int r = 0; r < 4; ++r) {
                const int srw = qr0 + g * 4 + r;
                const float v = po[dg][r] * __builtin_amdgcn_rcpf(l_[r]);
                ctx[((size_t)(b * SS + srw)) * DD + h * 64 + dg * 16 + r16] = f2bs(v);
            }
    }
}

// ---------------------------------------------------------------------------
extern "C" void kernel_launch(void* const* d_in, const int* in_sizes, int n_in,
                              void* d_out, int out_size, void* d_ws, size_t ws_size,
                              hipStream_t stream) {
    const float* query = (const float*)d_in[0];
    const float* key   = (const float*)d_in[1];
    const float* value = (const float*)d_in[2];
    // d_in[3] = mask (causal tril) -- implemented analytically
    const float* Wq = (const float*)d_in[4];
    const float* bq = (const float*)d_in[5];
    const float* Wk = (const float*)d_in[6];
    const float* bk = (const float*)d_in[7];
    const float* Wv = (const float*)d_in[8];
    const float* bv = (const float*)d_in[9];
    const float* Wo = (const float*)d_in[10];
    const float* bo = (const float*)d_in[11];
    float* out = (float*)d_out;

    const size_t elems = (size_t)BB * SS * DD;   // 4M
    const size_t wel   = (size_t)DD * DD;        // 1M
    short* qx  = (short*)d_ws;        // bf16 inputs
    short* kx  = qx + elems;
    short* vx  = kx + elems;
    short* wqx = vx + elems;          // bf16 weights
    short* wkx = wqx + wel;
    short* wvx = wkx + wel;
    short* wox = wvx + wel;
    short* qp  = wox + wel;           // projections
    short* kp  = qp + elems;
    short* vp  = kp + elems;
    // aliases (lifetime-disjoint):
    short* vT  = qx;                  // qx dead after QKV GEMM
    short* ctx = vx;                  // vx dead after QKV GEMM

    // 1) convert everything to bf16
    cvt_all<<<dim3(1024, 7), 256, 0, stream>>>(query, key, value, Wq, Wk, Wv, Wo,
                                               qx, kx, vx, wqx, wkx, wvx, wox);
    // 2) fused Q/K/V projections (768 blocks, XCD-panel decode, BK=64,
    //    swizzled LDS); 1/sqrt(DK) folded into Q
    gemm_nt_v2<128, 3, false><<<dim3(768), 256, 0, stream>>>(
        qx, kx, vx, wqx, wkx, wvx, bq, bk, bv, qp, kp, vp,
        0.125f, 1.0f, 1.0f, /*ppx=*/12, /*NY=*/32, /*KL=*/1024, DD, DD);
    // 3) V transpose per head (vT = qx region)
    mha_transpose_v<<<dim3(SS / 64, BB * HH), 256, 0, stream>>>(vp, vT);
    // 4) attention -> ctx (= vx region), double-buffered pipeline
    mha_attn<<<dim3(BB * HH, 16), 256, 0, stream>>>(qp, kp, vT, ctx);
    // 5) output projection, direct (BM=128, BN=64 -> 512 blocks = 2/CU)
    gemm_nt_v2<64, 4, true><<<dim3(512), 256, 0, stream>>>(
        ctx, ctx, ctx, wox, wox, wox, bo, bo, bo, out, out, out,
        1.0f, 1.0f, 1.0f, /*ppx=*/4, /*NY=*/32, /*KL=*/1024, DD, DD);
}